// Round 18
// baseline (75846.545 us; speedup 1.0000x reference)
//
#include <hip/hip_runtime.h>
#include <math.h>

#define Tn   16384
#define Mg   200
#define Nc   6
#define TOT  1200
#define Kk   25
#define Din  784
#define SP   28        // padded words per 24-cell block of sigma_sh
#define CHK  128       // real steps per chunk
#define WUP  160       // warmup steps (clamped at 0: early chunks run true prefix)
#define NCH  (Tn / CHK)
#define STSZ 2404      // floats per state slot: psi[1200], u[1200], alpha, pad(3)

// ---------------------------------------------------------------- transpose
__global__ void transpose_k(const float* __restrict__ src, float* __restrict__ dst,
                            int R, int C) {
    __shared__ float tile[32][33];
    int bx = blockIdx.x * 32, by = blockIdx.y * 32;
    int x = bx + threadIdx.x;
    for (int j = 0; j < 32; j += 8) {
        int y = by + threadIdx.y + j;
        if (x < C && y < R) tile[threadIdx.y + j][threadIdx.x] = src[(size_t)y * C + x];
    }
    __syncthreads();
    int x2 = by + threadIdx.x;
    for (int j = 0; j < 32; j += 8) {
        int y2 = bx + threadIdx.y + j;
        if (x2 < R && y2 < C) dst[(size_t)y2 * R + x2] = tile[threadIdx.x][threadIdx.y + j];
    }
}

// ------------------------------------------------- Za = X @ Wa^T + ba  (16384 x 200)
__global__ void za_k(const float* __restrict__ X, const float* __restrict__ Wa,
                     const float* __restrict__ ba, float* __restrict__ Za) {
    __shared__ float xs[16][788];
    const int tid = threadIdx.x;
    const int t0  = blockIdx.x * 16;
    for (int idx = tid; idx < 16 * Din; idx += 256) {
        int tt = idx / Din, kk = idx - tt * Din;
        xs[tt][kk] = X[(size_t)(t0 + tt) * Din + kk];
    }
    __syncthreads();
    const int tq = tid & 15, gq = tid >> 4;
    const float4* xrow = reinterpret_cast<const float4*>(&xs[tq][0]);
    for (int g = gq; g < Mg; g += 16) {
        float acc = ba[g];
        const float4* wrow = reinterpret_cast<const float4*>(Wa + (size_t)g * Din);
        for (int k4 = 0; k4 < Din / 4; ++k4) {
            float4 a = xrow[k4], b = wrow[k4];
            acc = fmaf(a.x, b.x, acc); acc = fmaf(a.y, b.y, acc);
            acc = fmaf(a.z, b.z, acc); acc = fmaf(a.w, b.w, acc);
        }
        Za[(size_t)(t0 + tq) * Mg + g] = acc;
    }
}

// ---------------------------------------------------------------- step engine
// Executes steps [tbeg, tend); YP written for t in [treal, tend). Optionally
// dumps state (psi,u,alpha) at top of step treal (dS) and after tend (dF).
// Same inlined body in chunk pass and repair pass -> identical rounding.
__device__ __forceinline__ void run_steps(
    int tbeg, int treal, int tend,
    const float* __restrict__ Za, const float* __restrict__ WbT,
    const float* __restrict__ bb, unsigned long long* __restrict__ YP,
    float* __restrict__ dS, float* __restrict__ dF,
    float* sigma_sh, float* minp, float* selD, int* selO, float* alphaS,
    float* ps, float4& uo, float& alpha)
{
    const int tid  = threadIdx.x;
    const int lane = tid & 63;

    if (tid < 64) {
        // ================= wave0: decision core =================
        const bool grp = (lane < 50);
        const int sgb  = lane * SP;
        const unsigned long long lt = (1ull << lane) - 1ull;
        unsigned long long thw = 0ull;
        int slotr[4] = {-1, -1, -1, -1};
        unsigned long long yv64[4] = {0ull, 0ull, 0ull, 0ull};
        int bj[4] = {0, 0, 0, 0};
        float dcl[4] = {0.f, 0.f, 0.f, 0.f};

        __syncthreads();                       // prologue: sigma ready

        for (int t = tbeg; t < tend; ++t) {
            if (dS && t == treal && grp) {
                #pragma unroll
                for (int i = 0; i < 24; ++i) dS[24 * lane + i] = ps[i];
            }
            // shadowed: YP stores of step t-1 (only in real range)
            if (t - 1 >= treal) {
                #pragma unroll
                for (int c = 0; c < 4; ++c)
                    if (slotr[c] >= 0) YP[(size_t)(t - 1) * Kk + slotr[c]] = yv64[c];
            }

            float4 mp4 = *reinterpret_cast<const float4*>(minp);
            float m = fminf(fminf(fminf(mp4.x, mp4.y), fminf(mp4.z, mp4.w)), minp[4]);
            const float m1 = 1.f - m;

            float sg[24];
            if (grp) {
                #pragma unroll
                for (int q = 0; q < 6; ++q) {
                    float4 v = *reinterpret_cast<const float4*>(sigma_sh + sgb + 4 * q);
                    sg[4*q] = v.x; sg[4*q+1] = v.y; sg[4*q+2] = v.z; sg[4*q+3] = v.w;
                }
            } else {
                #pragma unroll
                for (int i = 0; i < 24; ++i) sg[i] = 0.f;
            }

            float bs[4], bp[4]; unsigned long long kb[4];
            #pragma unroll
            for (int c = 0; c < 4; ++c) { bs[c]=0.f; bp[c]=0.f; bj[c]=0; kb[c]=0ull; }
            if (grp) {
                #pragma unroll
                for (int c = 0; c < 4; ++c) {
                    float best = -INFINITY, sbv = 0.f, pbv = 0.f; int jb = 0;
                    #pragma unroll
                    for (int j = 0; j < 6; ++j) {
                        int i = 6 * c + j;
                        float pv = (1.f - ps[i]) * (sg[i] + m1);
                        bool bet = pv > best;
                        best = bet ? pv : best;
                        jb  = bet ? j : jb;
                        sbv = bet ? sg[i] : sbv;
                        pbv = bet ? ps[i] : pbv;
                    }
                    unsigned ub = __float_as_uint(best);
                    ub ^= (unsigned)(((int)ub) >> 31) | 0x80000000u;
                    int g = 4 * lane + c;
                    kb[c] = ((unsigned long long)ub << 32) |
                            (unsigned long long)(0xFFFFFFFFu - (unsigned)g);
                    bs[c] = sbv; bp[c] = pbv; bj[c] = jb;
                }
            }

            // ballot quickselect, warm-started (exact regardless of pivot)
            unsigned long long A = 0ull, B = ~0ull;
            unsigned long long p = thw;
            unsigned long long theta;
            while (true) {
                int cnt = __popcll(__ballot(kb[0] >= p)) + __popcll(__ballot(kb[1] >= p))
                        + __popcll(__ballot(kb[2] >= p)) + __popcll(__ballot(kb[3] >= p));
                if (cnt == Kk) { theta = p; break; }
                if (cnt > Kk) A = p; else B = p;
                unsigned long long m0 = __ballot(kb[0] > A && kb[0] < B);
                unsigned long long m1b = __ballot(kb[1] > A && kb[1] < B);
                unsigned long long m2 = __ballot(kb[2] > A && kb[2] < B);
                unsigned long long m3 = __ballot(kb[3] > A && kb[3] < B);
                int cls; unsigned long long mm;
                if (m0)       { cls = 0; mm = m0; }
                else if (m1b) { cls = 1; mm = m1b; }
                else if (m2)  { cls = 2; mm = m2; }
                else          { cls = 3; mm = m3; }
                int sl = __ffsll(mm) - 1;
                unsigned long long kc = (cls==0)?kb[0]:(cls==1)?kb[1]:(cls==2)?kb[2]:kb[3];
                p = __shfl(kc, sl);
            }
            thw = theta;

            unsigned long long M0 = __ballot(kb[0] >= theta);
            unsigned long long M1 = __ballot(kb[1] >= theta);
            unsigned long long M2 = __ballot(kb[2] >= theta);
            unsigned long long M3 = __ballot(kb[3] >= theta);
            int base1 = __popcll(M0);
            int base2 = base1 + __popcll(M1);
            int base3 = base2 + __popcll(M2);

            #pragma unroll
            for (int c = 0; c < 4; ++c) {
                slotr[c] = -1;
                unsigned long long Mc = (c==0)?M0:(c==1)?M1:(c==2)?M2:M3;
                int bse = (c==0)?0:(c==1)?base1:(c==2)?base2:base3;
                bool s = grp && (kb[c] >= theta);
                float d = 0.f;
                if (s) {
                    int slot = bse + __popcll(Mc & lt);
                    float x = fminf(fmaxf(bs[c], -9.f), 9.f);
                    float e = __expf(2.f * x);
                    float y = 1.f - 2.f / (e + 1.f);
                    float yv = fmaxf(y, 0.f);
                    d = fmaxf(y - 0.5f * bp[c], 0.f);
                    int g = 4 * lane + c;
                    selD[slot] = d;
                    selO[slot] = (6 * g + bj[c]) * TOT;
                    slotr[c] = slot;
                    yv64[c] = ((unsigned long long)(unsigned)g << 32) |
                              (unsigned long long)__float_as_uint(yv);
                }
                dcl[c] = d;
            }

            __syncthreads();                   // bar A: sel published

            if (grp) {                          // shadowed psi update
                #pragma unroll
                for (int c = 0; c < 4; ++c) {
                    #pragma unroll
                    for (int j = 0; j < 6; ++j) {
                        int i = 6 * c + j;
                        float add = (j == bj[c]) ? dcl[c] : 0.f;
                        ps[i] = fmaf(ps[i], 0.5f, add);
                    }
                }
            }

            __syncthreads();                   // bar B: sigma_{t+1} ready
        }

        #pragma unroll
        for (int c = 0; c < 4; ++c)
            if (slotr[c] >= 0) YP[(size_t)(tend - 1) * Kk + slotr[c]] = yv64[c];
        if (dF && grp) {
            #pragma unroll
            for (int i = 0; i < 24; ++i) dF[24 * lane + i] = ps[i];
        }
    } else {
        // ================= waves 1-5: gather + alpha + sigma =================
        const int j = tid - 64;
        const bool act = (j < 300);
        const int w = (tid >> 6) - 1;
        const int base = act ? 4 * j : 0;
        const int saddr = act ? ((j / 6) * SP + (4 * j) % 24) : 0;
        const int g0 = base / 6, g1 = (base + 3) / 6;
        const bool f1 = ((base + 1) / 6) != g0;
        const bool f2 = ((base + 2) / 6) != g0;
        const bool f3 = ((base + 3) / 6) != g0;

        float4 cb4 = make_float4(0.f, 0.f, 0.f, 0.f);
        if (act) cb4 = *reinterpret_cast<const float4*>(bb + base);

        // prologue: sigma at tbeg from provided (uo, alpha) -- identical
        // expression to the in-loop sigma computation -> identical rounding
        {
            float za0 = act ? Za[(size_t)tbeg * Mg + g0] : 0.f;
            float za1 = act ? Za[(size_t)tbeg * Mg + g1] : 0.f;
            const float A0  = (alpha == 0.f) ? 1.f : alpha;
            const float inv = 1.f / A0;
            float s0 = fmaf(uo.x, inv, cb4.x + za0);
            float s1 = fmaf(uo.y, inv, cb4.y + (f1 ? za1 : za0));
            float s2 = fmaf(uo.z, inv, cb4.z + (f2 ? za1 : za0));
            float s3 = fmaf(uo.w, inv, cb4.w + (f3 ? za1 : za0));
            if (act)
                *reinterpret_cast<float4*>(sigma_sh + saddr) = make_float4(s0,s1,s2,s3);
            float lm = act ? fminf(fminf(s0, s1), fminf(s2, s3)) : INFINITY;
            #pragma unroll
            for (int o = 1; o < 64; o <<= 1) lm = fminf(lm, __shfl_xor(lm, o));
            if (lane == 0) minp[w] = lm;
        }
        __syncthreads();                        // prologue barrier

        for (int t = tbeg; t < tend; ++t) {
            if (dS && t == treal) {
                if (act) *reinterpret_cast<float4*>(dS + 1200 + base) = uo;
                if (tid == 64) dS[2400] = alpha;
            }
            uo.x *= 0.5f; uo.y *= 0.5f; uo.z *= 0.5f; uo.w *= 0.5f;

            __syncthreads();                    // bar A: sel ready

            float vD = 0.f; int vO = 0;
            if (lane < 25) { vD = selD[lane]; vO = selO[lane]; }

            const int tn = (t + 1 < tend) ? t + 1 : t;
            float nza0 = act ? Za[(size_t)tn * Mg + g0] : 0.f;
            float nza1 = act ? Za[(size_t)tn * Mg + g1] : 0.f;
            float4 cc[Kk];
            #pragma unroll
            for (int k = 0; k < Kk; ++k) {
                int offk = __builtin_amdgcn_readlane(vO, k);
                cc[k] = *reinterpret_cast<const float4*>(WbT + offk + base);
            }
            __builtin_amdgcn_sched_barrier(0);

            float av = vD;
            #pragma unroll
            for (int o = 1; o < 64; o <<= 1) av += __shfl_xor(av, o);
            alpha = fmaf(alpha, 0.5f, av);
            const float A0  = (alpha == 0.f) ? 1.f : alpha;
            const float inv = 1.f / A0;
            if (tid == 64) *alphaS = alpha;

            #pragma unroll
            for (int k = 0; k < Kk; ++k) {
                float dk = __uint_as_float(
                    (unsigned)__builtin_amdgcn_readlane((int)__float_as_uint(vD), k));
                uo.x = fmaf(dk, cc[k].x, uo.x);
                uo.y = fmaf(dk, cc[k].y, uo.y);
                uo.z = fmaf(dk, cc[k].z, uo.z);
                uo.w = fmaf(dk, cc[k].w, uo.w);
            }

            float s0 = fmaf(uo.x, inv, cb4.x + nza0);
            float s1 = fmaf(uo.y, inv, cb4.y + (f1 ? nza1 : nza0));
            float s2 = fmaf(uo.z, inv, cb4.z + (f2 ? nza1 : nza0));
            float s3 = fmaf(uo.w, inv, cb4.w + (f3 ? nza1 : nza0));
            if (act)
                *reinterpret_cast<float4*>(sigma_sh + saddr) = make_float4(s0,s1,s2,s3);
            float lm = act ? fminf(fminf(s0, s1), fminf(s2, s3)) : INFINITY;
            #pragma unroll
            for (int o = 1; o < 64; o <<= 1) lm = fminf(lm, __shfl_xor(lm, o));
            if (lane == 0) minp[w] = lm;

            __syncthreads();                    // bar B: sigma published
        }
        if (dF) {
            if (act) *reinterpret_cast<float4*>(dF + 1200 + base) = uo;
            if (tid == 64) dF[2400] = alpha;
        }
    }
}

// ------------------------------------------------------- pass 1: parallel chunks
__launch_bounds__(384, 1)
__global__ void chunk_k(const float* __restrict__ Za, const float* __restrict__ WbT,
                        const float* __restrict__ bb,
                        unsigned long long* __restrict__ YP,
                        float* __restrict__ Sst, float* __restrict__ Fst) {
    __shared__ alignas(16) float sigma_sh[50 * SP];
    __shared__ alignas(16) float minp[8];
    __shared__ alignas(16) float selD[32];
    __shared__ alignas(16) int   selO[32];
    __shared__ float alphaS;

    const int chk = blockIdx.x;
    const int treal = chk * CHK;
    int tbeg = treal - WUP;                   // R16/R17 BUG: went negative for
    if (tbeg < 0) tbeg = 0;                   // chk>=1 when WUP>CHK -> OOB fault
    const int tend  = treal + CHK;

    float ps[24];
    #pragma unroll
    for (int i = 0; i < 24; ++i) ps[i] = 0.f;
    float4 uo = make_float4(0.f, 0.f, 0.f, 0.f);
    float alpha = 0.f;

    run_steps(tbeg, treal, tend, Za, WbT, bb, YP,
              Sst + (size_t)chk * STSZ, Fst + (size_t)chk * STSZ,
              sigma_sh, minp, selD, selO, &alphaS, ps, uo, alpha);
}

// ------------------------------------------- pass 2: exact verify/repair chain
__launch_bounds__(384, 1)
__global__ void repair_k(const float* __restrict__ Za, const float* __restrict__ WbT,
                         const float* __restrict__ bb,
                         unsigned long long* __restrict__ YP,
                         const float* __restrict__ Sst, const float* __restrict__ Fst,
                         float* __restrict__ outTail) {
    __shared__ alignas(16) float sigma_sh[50 * SP];
    __shared__ alignas(16) float minp[8];
    __shared__ alignas(16) float selD[32];
    __shared__ alignas(16) int   selO[32];
    __shared__ float alphaS;
    __shared__ int okS;

    const int tid  = threadIdx.x;
    const int lane = tid & 63;

    // exact state E, distributed exactly as run_steps expects
    float ps[24];
    #pragma unroll
    for (int i = 0; i < 24; ++i) ps[i] = 0.f;
    float4 uo = make_float4(0.f, 0.f, 0.f, 0.f);
    float alpha = 0.f;

    for (int c = 0; c < NCH; ++c) {
        if (tid == 0) okS = 1;
        __syncthreads();

        const float* S = Sst + (size_t)c * STSZ;
        int ok = 1;
        if (tid < 64) {
            if (lane < 50) {
                #pragma unroll
                for (int i = 0; i < 24; ++i)
                    ok &= (__float_as_uint(ps[i]) == __float_as_uint(S[24 * lane + i]));
            }
        } else {
            const int j = tid - 64;
            if (j < 300) {
                const float* up = S + 1200 + 4 * j;
                ok &= (__float_as_uint(uo.x) == __float_as_uint(up[0]));
                ok &= (__float_as_uint(uo.y) == __float_as_uint(up[1]));
                ok &= (__float_as_uint(uo.z) == __float_as_uint(up[2]));
                ok &= (__float_as_uint(uo.w) == __float_as_uint(up[3]));
            }
            if (tid == 64)
                ok &= (__float_as_uint(alpha) == __float_as_uint(S[2400]));
        }
        if (!ok) okS = 0;
        __syncthreads();
        const int good = okS;
        __syncthreads();                       // reads done before next okS write

        if (good) {
            // adopt chunk's results: E <- FIN[c] (YP range already correct)
            const float* F = Fst + (size_t)c * STSZ;
            if (tid < 64) {
                if (lane < 50) {
                    #pragma unroll
                    for (int i = 0; i < 24; ++i) ps[i] = F[24 * lane + i];
                }
            } else {
                const int j = tid - 64;
                if (j < 300) uo = *reinterpret_cast<const float4*>(F + 1200 + 4 * j);
                alpha = F[2400];
            }
        } else {
            // recompute chunk c exactly from E (overwrites YP range; updates E)
            run_steps(c * CHK, c * CHK, (c + 1) * CHK, Za, WbT, bb, YP,
                      nullptr, nullptr, sigma_sh, minp, selD, selO, &alphaS,
                      ps, uo, alpha);
        }
    }

    // epilogue: x_b, phi, psi from exact final state
    __syncthreads();
    if (tid == 64) alphaS = alpha;
    __syncthreads();
    if (tid < 64 && lane < 50) {
        const int cell0 = 24 * lane;
        float a = alphaS;
        float inv2 = (a == 0.f) ? 1.f : (1.f / a);
        #pragma unroll
        for (int i = 0; i < 24; ++i) {
            outTail[cell0 + i]           = ps[i] * inv2;
            outTail[TOT + cell0 + i]     = ps[i];
            outTail[2 * TOT + cell0 + i] = ps[i];
        }
    }
}

// ------------------------------------------------- preds = bd + sum val * WdT[idx]
__global__ void preds_k(const unsigned long long* __restrict__ YP,
                        const float* __restrict__ WdT, const float* __restrict__ bd,
                        float* __restrict__ out) {
    const int t = blockIdx.x;
    __shared__ float sv[Kk];
    __shared__ int   si[Kk];
    if (threadIdx.x < Kk) {
        unsigned long long v = YP[(size_t)t * Kk + threadIdx.x];
        sv[threadIdx.x] = __uint_as_float((unsigned)v);
        si[threadIdx.x] = (int)(v >> 32);
    }
    __syncthreads();
    for (int d = threadIdx.x; d < Din; d += 256) {
        float acc = bd[d];
        #pragma unroll
        for (int k = 0; k < Kk; ++k)
            acc = fmaf(sv[k], WdT[(size_t)si[k] * Din + d], acc);
        out[(size_t)t * Din + d] = acc;
    }
}

extern "C" void kernel_launch(void* const* d_in, const int* in_sizes, int n_in,
                              void* d_out, int out_size, void* d_ws, size_t ws_size,
                              hipStream_t stream) {
    const float* X  = (const float*)d_in[0];
    const float* Wa = (const float*)d_in[1];
    const float* ba = (const float*)d_in[2];
    const float* Wb = (const float*)d_in[3];
    const float* bb = (const float*)d_in[4];
    const float* Wd = (const float*)d_in[5];
    const float* bd = (const float*)d_in[6];
    float* out = (float*)d_out;

    // Workspace layout (24.6 MB total; WdT ALIASES the Sst/Fst region --
    // state dumps are dead before preds_k needs WdT, transposed after repair):
    float* w    = (float*)d_ws;
    float* Za   = w;                                    // 16384*200      13.11 MB
    float* WbT  = Za  + (size_t)Tn * Mg;                // 1200*1200       5.76 MB
    unsigned long long* YP =
        (unsigned long long*)(WbT + (size_t)TOT * TOT); // 16384*25 u64    3.28 MB
    float* Sst  = (float*)(YP + (size_t)Tn * Kk);       // NCH*STSZ        1.23 MB
    float* Fst  = Sst + (size_t)NCH * STSZ;             // NCH*STSZ        1.23 MB
    float* WdT  = Sst;                                  // 200*784 (alias) 0.63 MB

    dim3 tb(32, 8);
    transpose_k<<<dim3((TOT + 31) / 32, (TOT + 31) / 32), tb, 0, stream>>>(Wb, WbT, TOT, TOT);
    za_k<<<Tn / 16, 256, 0, stream>>>(X, Wa, ba, Za);
    chunk_k<<<NCH, 384, 0, stream>>>(Za, WbT, bb, YP, Sst, Fst);
    repair_k<<<1, 384, 0, stream>>>(Za, WbT, bb, YP, Sst, Fst, out + (size_t)Tn * Din);
    // Sst/Fst now dead -> transpose Wd into the aliased region for preds_k
    transpose_k<<<dim3((Mg + 31) / 32, (Din + 31) / 32), tb, 0, stream>>>(Wd, WdT, Din, Mg);
    preds_k<<<Tn, 256, 0, stream>>>(YP, WdT, bd, out);
}